// Round 1
// baseline (1101.202 us; speedup 1.0000x reference)
//
#include <hip/hip_runtime.h>
#include <math.h>

// Geometry (fixed by the problem)
#define CDIM  512
#define NTOK  4096
#define MTOK  1024
#define NHEAD 8
#define HD    64
#define HS    32   // H/SR
#define WS    32   // W/SR
#define K2    2048 // 4*C conv reduction

// ---------------- fp32 tiled GEMM:  C = (A @ B + bias) * mask[row] ----------------
// A: [Ma,K] row-major, B: [K,Nb] row-major, C: [Ma,Nb].
#define BM 64
#define BN 64
#define BK 16

__global__ __launch_bounds__(256) void gemm_f32(
    const float* __restrict__ A, const float* __restrict__ B,
    const float* __restrict__ bias, const float* __restrict__ mask,
    float* __restrict__ C, int Ma, int K, int Nb) {
  __shared__ float As[BK][BM];   // transposed A tile
  __shared__ float Bs[BK][BN];
  const int t = threadIdx.x;
  const int row0 = blockIdx.y * BM;
  const int col0 = blockIdx.x * BN;
  const int tx = t & 15;         // output col group
  const int ty = t >> 4;         // output row group
  const int am = t >> 2, ak = t & 3;   // A tile load: row am, float4 col ak
  const int bk = t >> 4, bn = t & 15;  // B tile load: row bk, float4 col bn

  float acc[4][4] = {};
  for (int k0 = 0; k0 < K; k0 += BK) {
    float4 av = *(const float4*)(A + (size_t)(row0 + am) * K + k0 + ak * 4);
    As[ak * 4 + 0][am] = av.x;
    As[ak * 4 + 1][am] = av.y;
    As[ak * 4 + 2][am] = av.z;
    As[ak * 4 + 3][am] = av.w;
    *(float4*)&Bs[bk][bn * 4] =
        *(const float4*)(B + (size_t)(k0 + bk) * Nb + col0 + bn * 4);
    __syncthreads();
#pragma unroll
    for (int kk = 0; kk < BK; ++kk) {
      float a0 = As[kk][ty * 4 + 0];
      float a1 = As[kk][ty * 4 + 1];
      float a2 = As[kk][ty * 4 + 2];
      float a3 = As[kk][ty * 4 + 3];
      float b0 = Bs[kk][tx * 4 + 0];
      float b1 = Bs[kk][tx * 4 + 1];
      float b2 = Bs[kk][tx * 4 + 2];
      float b3 = Bs[kk][tx * 4 + 3];
      acc[0][0] = fmaf(a0, b0, acc[0][0]); acc[0][1] = fmaf(a0, b1, acc[0][1]);
      acc[0][2] = fmaf(a0, b2, acc[0][2]); acc[0][3] = fmaf(a0, b3, acc[0][3]);
      acc[1][0] = fmaf(a1, b0, acc[1][0]); acc[1][1] = fmaf(a1, b1, acc[1][1]);
      acc[1][2] = fmaf(a1, b2, acc[1][2]); acc[1][3] = fmaf(a1, b3, acc[1][3]);
      acc[2][0] = fmaf(a2, b0, acc[2][0]); acc[2][1] = fmaf(a2, b1, acc[2][1]);
      acc[2][2] = fmaf(a2, b2, acc[2][2]); acc[2][3] = fmaf(a2, b3, acc[2][3]);
      acc[3][0] = fmaf(a3, b0, acc[3][0]); acc[3][1] = fmaf(a3, b1, acc[3][1]);
      acc[3][2] = fmaf(a3, b2, acc[3][2]); acc[3][3] = fmaf(a3, b3, acc[3][3]);
    }
    __syncthreads();
  }
#pragma unroll
  for (int i = 0; i < 4; ++i) {
    int row = row0 + ty * 4 + i;
    int col = col0 + tx * 4;
    float mval = mask ? mask[row] : 1.0f;
    float4 o;
    o.x = acc[i][0]; o.y = acc[i][1]; o.z = acc[i][2]; o.w = acc[i][3];
    if (bias) {
      o.x += bias[col + 0]; o.y += bias[col + 1];
      o.z += bias[col + 2]; o.w += bias[col + 3];
    }
    o.x *= mval; o.y *= mval; o.z *= mval; o.w *= mval;
    *(float4*)(C + (size_t)row * Nb + col) = o;
  }
}

// ---------------- Wsr [O=512,I=512,2,2] -> W2 [r=2048, O=512], r = p*512 + i ----------------
__global__ __launch_bounds__(256) void wsr_t(const float* __restrict__ Wsr,
                                             float* __restrict__ W2) {
  int idx = blockIdx.x * 256 + threadIdx.x;  // 2048*512
  int r = idx >> 9;
  int o = idx & 511;
  int p = r >> 9;       // kh*2+kw
  int i = r & 511;
  W2[idx] = Wsr[(size_t)o * 2048 + i * 4 + p];
}

// ---------------- patch gather: Ap [m=1024, r=2048], r = p*512 + i ----------------
__global__ __launch_bounds__(256) void patches_f32(const float* __restrict__ x,
                                                   float* __restrict__ Ap) {
  int idx = blockIdx.x * 256 + threadIdx.x;  // 1024*2048
  int m = idx >> 11;
  int r = idx & 2047;
  int p = r >> 9;
  int i = r & 511;
  int hh = m >> 5, ww = m & 31;
  int kh = p >> 1, kw = p & 1;
  int token = (2 * hh + kh) * 64 + 2 * ww + kw;
  Ap[idx] = x[(size_t)token * CDIM + i];
}

// ---------------- LayerNorm over channels, row per block ----------------
__global__ __launch_bounds__(256) void ln_f32(const float* __restrict__ xr,
                                              const float* __restrict__ gamma,
                                              const float* __restrict__ beta,
                                              float* __restrict__ xn) {
  const int row = blockIdx.x;
  const int t = threadIdx.x;
  float v0 = xr[(size_t)row * CDIM + t * 2 + 0];
  float v1 = xr[(size_t)row * CDIM + t * 2 + 1];
  float s = v0 + v1;
  float sq = v0 * v0 + v1 * v1;
#pragma unroll
  for (int m = 1; m < 64; m <<= 1) {
    s += __shfl_xor(s, m, 64);
    sq += __shfl_xor(sq, m, 64);
  }
  __shared__ float ls[4], lsq[4];
  if ((t & 63) == 0) { ls[t >> 6] = s; lsq[t >> 6] = sq; }
  __syncthreads();
  s = ls[0] + ls[1] + ls[2] + ls[3];
  sq = lsq[0] + lsq[1] + lsq[2] + lsq[3];
  float mean = s * (1.0f / CDIM);
  float var = sq * (1.0f / CDIM) - mean * mean;
  float rs = rsqrtf(var + 1e-5f);
  int c = t * 2;
  xn[(size_t)row * CDIM + c + 0] = (v0 - mean) * rs * gamma[c + 0] + beta[c + 0];
  xn[(size_t)row * CDIM + c + 1] = (v1 - mean) * rs * gamma[c + 1] + beta[c + 1];
}

// ---------------- flash attention fp32 ----------------
// q: [N, C] (head h at cols h*64..), kv: [M, 2C] (k at h*64, v at 512+h*64)
// ao: [N, C]. Block: 32 queries x one head; 256 threads = 32 q x 8 dim-groups.
__global__ __launch_bounds__(256) void attn_f32(const float* __restrict__ q,
                                                const float* __restrict__ kv,
                                                float* __restrict__ ao) {
  const int h = blockIdx.y;
  const int n0 = blockIdx.x * 32;
  const int t = threadIdx.x;
  const int qi = t >> 3;  // 0..31 query
  const int dg = t & 7;   // dims dg*8..dg*8+7

  __shared__ float Ks[16][64];
  __shared__ float Vs[16][64];
  __shared__ float Ps[32][17];

  float qreg[8];
  {
    const float* qp = q + (size_t)(n0 + qi) * CDIM + h * HD + dg * 8;
    float4 qa = *(const float4*)qp;
    float4 qb = *(const float4*)(qp + 4);
    const float scale = 0.125f;  // hd^-0.5
    qreg[0] = qa.x * scale; qreg[1] = qa.y * scale;
    qreg[2] = qa.z * scale; qreg[3] = qa.w * scale;
    qreg[4] = qb.x * scale; qreg[5] = qb.y * scale;
    qreg[6] = qb.z * scale; qreg[7] = qb.w * scale;
  }

  float o[8] = {};
  float mrun = -1e30f, lrun = 0.0f;
  const int lr = t >> 4, lc = t & 15;

  for (int m0 = 0; m0 < MTOK; m0 += 16) {
    *(float4*)&Ks[lr][lc * 4] =
        *(const float4*)&kv[(size_t)(m0 + lr) * 1024 + h * HD + lc * 4];
    *(float4*)&Vs[lr][lc * 4] =
        *(const float4*)&kv[(size_t)(m0 + lr) * 1024 + 512 + h * HD + lc * 4];
    __syncthreads();

    float s[16];
#pragma unroll
    for (int k = 0; k < 16; ++k) {
      float a = 0.0f;
#pragma unroll
      for (int j = 0; j < 8; ++j) a = fmaf(qreg[j], Ks[k][dg * 8 + j], a);
      s[k] = a;
    }
#pragma unroll
    for (int msk = 1; msk <= 4; msk <<= 1) {
#pragma unroll
      for (int k = 0; k < 16; ++k) s[k] += __shfl_xor(s[k], msk, 64);
    }
    float tmax = s[0];
#pragma unroll
    for (int k = 1; k < 16; ++k) tmax = fmaxf(tmax, s[k]);
    float mnew = fmaxf(mrun, tmax);
    float corr = __expf(mrun - mnew);
    Ps[qi][dg * 2 + 0] = __expf(s[dg * 2 + 0] - mnew);
    Ps[qi][dg * 2 + 1] = __expf(s[dg * 2 + 1] - mnew);
    __syncthreads();

    float sump = 0.0f;
#pragma unroll
    for (int j = 0; j < 8; ++j) o[j] *= corr;
#pragma unroll
    for (int k = 0; k < 16; ++k) {
      float p = Ps[qi][k];
      sump += p;
#pragma unroll
      for (int j = 0; j < 8; ++j) o[j] = fmaf(p, Vs[k][dg * 8 + j], o[j]);
    }
    lrun = lrun * corr + sump;
    mrun = mnew;
    __syncthreads();
  }

  float inv = 1.0f / lrun;
  float* op = ao + (size_t)(n0 + qi) * CDIM + h * HD + dg * 8;
  float4 oa, ob;
  oa.x = o[0] * inv; oa.y = o[1] * inv; oa.z = o[2] * inv; oa.w = o[3] * inv;
  ob.x = o[4] * inv; ob.y = o[5] * inv; ob.z = o[6] * inv; ob.w = o[7] * inv;
  *(float4*)op = oa;
  *(float4*)(op + 4) = ob;
}

// ---------------- token exchange (in-place on d_out halves) ----------------
__global__ __launch_bounds__(256) void exchange_f32(float* __restrict__ out,
                                                    const float* __restrict__ mask0,
                                                    const float* __restrict__ mask1) {
  int idx = blockIdx.x * 256 + threadIdx.x;  // 4096*512
  int n = idx >> 9;
  float o0 = out[idx];
  float o1 = out[idx + NTOK * CDIM];
  bool k0 = mask0[n] >= 0.02f;
  bool k1 = mask1[n] >= 0.02f;
  out[idx] = k0 ? o0 : o1;
  out[idx + NTOK * CDIM] = k1 ? o1 : o0;
}

extern "C" void kernel_launch(void* const* d_in, const int* in_sizes, int n_in,
                              void* d_out, int out_size, void* d_ws, size_t ws_size,
                              hipStream_t stream) {
  const float* x0    = (const float*)d_in[0];
  const float* x1    = (const float*)d_in[1];
  const float* mask0 = (const float*)d_in[2];
  const float* mask1 = (const float*)d_in[3];
  const float* Wq    = (const float*)d_in[4];
  const float* Wkv   = (const float*)d_in[5];
  const float* Wsr   = (const float*)d_in[6];
  const float* bsr   = (const float*)d_in[7];
  const float* gamma = (const float*)d_in[8];
  const float* beta  = (const float*)d_in[9];
  const float* Wp    = (const float*)d_in[10];
  const float* bp    = (const float*)d_in[11];

  float* ws  = (float*)d_ws;
  float* q0  = ws;                 // 4096*512
  float* q1  = q0  + 2097152;
  float* Ap0 = q1  + 2097152;      // 1024*2048
  float* Ap1 = Ap0 + 2097152;
  float* W2  = Ap1 + 2097152;      // 2048*512
  float* xr0 = W2  + 1048576;      // 1024*512
  float* xr1 = xr0 + 524288;
  float* xn0 = xr1 + 524288;
  float* xn1 = xn0 + 524288;
  float* kv0 = xn1 + 524288;       // 1024*1024
  float* kv1 = kv0 + 1048576;
  float* ao0 = kv1 + 1048576;      // 4096*512
  float* ao1 = ao0 + 2097152;

  float* out0 = (float*)d_out;
  float* out1 = out0 + 2097152;

  dim3 blk(256);

  // prep
  wsr_t<<<1048576 / 256, blk, 0, stream>>>(Wsr, W2);
  patches_f32<<<2097152 / 256, blk, 0, stream>>>(x0, Ap0);
  patches_f32<<<2097152 / 256, blk, 0, stream>>>(x1, Ap1);

  // q projection: [4096,512] @ [512,512]
  gemm_f32<<<dim3(CDIM / BN, NTOK / BM), blk, 0, stream>>>(x0, Wq, nullptr, nullptr, q0, NTOK, CDIM, CDIM);
  gemm_f32<<<dim3(CDIM / BN, NTOK / BM), blk, 0, stream>>>(x1, Wq, nullptr, nullptr, q1, NTOK, CDIM, CDIM);

  // SR conv as GEMM: [1024,2048] @ [2048,512] + bsr
  gemm_f32<<<dim3(CDIM / BN, MTOK / BM), blk, 0, stream>>>(Ap0, W2, bsr, nullptr, xr0, MTOK, K2, CDIM);
  gemm_f32<<<dim3(CDIM / BN, MTOK / BM), blk, 0, stream>>>(Ap1, W2, bsr, nullptr, xr1, MTOK, K2, CDIM);

  // LayerNorm
  ln_f32<<<MTOK, blk, 0, stream>>>(xr0, gamma, beta, xn0);
  ln_f32<<<MTOK, blk, 0, stream>>>(xr1, gamma, beta, xn1);

  // kv projection: [1024,512] @ [512,1024]
  gemm_f32<<<dim3(1024 / BN, MTOK / BM), blk, 0, stream>>>(xn0, Wkv, nullptr, nullptr, kv0, MTOK, CDIM, 1024);
  gemm_f32<<<dim3(1024 / BN, MTOK / BM), blk, 0, stream>>>(xn1, Wkv, nullptr, nullptr, kv1, MTOK, CDIM, 1024);

  // attention
  attn_f32<<<dim3(NTOK / 32, NHEAD), blk, 0, stream>>>(q0, kv0, ao0);
  attn_f32<<<dim3(NTOK / 32, NHEAD), blk, 0, stream>>>(q1, kv1, ao1);

  // output projection + bias + mask
  gemm_f32<<<dim3(CDIM / BN, NTOK / BM), blk, 0, stream>>>(ao0, Wp, bp, mask0, out0, NTOK, CDIM, CDIM);
  gemm_f32<<<dim3(CDIM / BN, NTOK / BM), blk, 0, stream>>>(ao1, Wp, bp, mask1, out1, NTOK, CDIM, CDIM);

  // token exchange
  exchange_f32<<<2097152 / 256, blk, 0, stream>>>(out0, mask0, mask1);
}

// Round 2
// 304.853 us; speedup vs baseline: 3.6122x; 3.6122x over previous
//
#include <hip/hip_runtime.h>
#include <math.h>

typedef unsigned short u16;
typedef unsigned int u32;
typedef unsigned long long u64;
typedef __attribute__((ext_vector_type(8))) short short8;
typedef __attribute__((ext_vector_type(4))) float f32x4;

#define CDIM 512
#define NTOK 4096
#define MTOK 1024
#define NHEAD 8

// ---------- bf16 helpers ----------
__device__ __forceinline__ u16 f2bf(float x) {
  u32 b = __float_as_uint(x);
  u32 r = (b + 0x7FFFu + ((b >> 16) & 1u)) >> 16;
  return (u16)r;
}
__device__ __forceinline__ float bf2f(u16 u) {
  return __uint_as_float(((u32)u) << 16);
}

__device__ __forceinline__ void gload16(const void* g, void* l) {
  __builtin_amdgcn_global_load_lds(
      (const __attribute__((address_space(1))) u32*)g,
      (__attribute__((address_space(3))) u32*)l, 16, 0, 0);
}

// ---------- weight transpose+split: src [K=512][N] f32 -> dh/dl [N][512] bf16 ----------
__global__ __launch_bounds__(256) void tsplit(const float* __restrict__ src,
                                              u16* __restrict__ dh, u16* __restrict__ dl,
                                              int N) {
  int idx = blockIdx.x * 256 + threadIdx.x;  // N*512
  int n = idx >> 9, k = idx & 511;
  float v = src[(size_t)k * N + n];
  u16 hi = f2bf(v);
  dh[idx] = hi;
  dl[idx] = f2bf(v - bf2f(hi));
}

// ---------- Wsr [O=512][I=512][2][2] -> W2T [O=512][r=2048], r = p*512+i ----------
__global__ __launch_bounds__(256) void wsr_split(const float* __restrict__ Wsr,
                                                 u16* __restrict__ dh, u16* __restrict__ dl) {
  int idx = blockIdx.x * 256 + threadIdx.x;  // 512*2048
  int o = idx >> 11, r = idx & 2047;
  int p = r >> 9, i = r & 511;
  float v = Wsr[(size_t)o * 2048 + i * 4 + p];
  u16 hi = f2bf(v);
  dh[idx] = hi;
  dl[idx] = f2bf(v - bf2f(hi));
}

// ---------- generic f32 -> bf16 hi/lo split ----------
__global__ __launch_bounds__(256) void fsplit(const float* __restrict__ src,
                                              u16* __restrict__ dh, u16* __restrict__ dl) {
  int idx = blockIdx.x * 256 + threadIdx.x;
  float v = src[idx];
  u16 hi = f2bf(v);
  dh[idx] = hi;
  dl[idx] = f2bf(v - bf2f(hi));
}

// ---------- split-bf16 MFMA GEMM ----------
// A (per branch): [M][K] bf16 hi/lo (or gather from x for conv). BT: [N][K] bf16 hi/lo.
// C = A@B. modes: 0 = f32 store at Of + bz*M*N; 1 = f32 (+bias)*mask at Of + br*M*N;
//               2 = bf16(acc*oscale) at Ob + br*M*N.
__global__ __launch_bounds__(256) void gemm_sp(
    const u16* __restrict__ A0h, const u16* __restrict__ A0l,
    const u16* __restrict__ A1h, const u16* __restrict__ A1l,
    const u16* __restrict__ BTh, const u16* __restrict__ BTl,
    int M, int N, int K, int kc, int nk, int mode,
    float* __restrict__ Of, u16* __restrict__ Ob,
    const float* __restrict__ bias,
    const float* __restrict__ mask0, const float* __restrict__ mask1,
    float oscale, int gather) {
  const int t = threadIdx.x;
  const int w = t >> 6;
  const int l = t & 63;
  const int lr = l & 15;
  const int lc = l >> 4;
  const int bz = blockIdx.z;
  const int br = bz / nk, kcid = bz % nk;
  const int row0 = blockIdx.y * 128;
  const int col0 = blockIdx.x * 128;
  const int koff = kcid * kc;
  const u16* Ah = br ? A1h : A0h;
  const u16* Al = br ? A1l : A0l;

  __shared__ u16 sAh[4096], sAl[4096], sBh[4096], sBl[4096];  // 8 frags x 512 each

  f32x4 acc[4][4];
#pragma unroll
  for (int a = 0; a < 4; ++a)
#pragma unroll
    for (int b = 0; b < 4; ++b) acc[a][b] = (f32x4){0.f, 0.f, 0.f, 0.f};

  for (int k0 = koff; k0 < koff + kc; k0 += 32) {
    // stage: wave w stages frags 2w, 2w+1 of each of the 4 tiles
#pragma unroll
    for (int i = 0; i < 2; ++i) {
      const int f = w * 2 + i;
      const int ar = f * 16 + lr;
      size_t ga;
      if (gather) {
        const int k = k0 + lc * 8;
        const int p = k >> 9;
        const int ii = k & 511;
        const int m = row0 + ar;
        const int token = (((m >> 5) * 2 + (p >> 1)) << 6) + ((m & 31) * 2 + (p & 1));
        ga = (size_t)token * 512 + ii;
      } else {
        ga = (size_t)(row0 + ar) * K + k0 + lc * 8;
      }
      gload16(Ah + ga, (void*)&sAh[f * 512]);
      gload16(Al + ga, (void*)&sAl[f * 512]);
      const size_t gb = (size_t)(col0 + ar) * K + k0 + lc * 8;
      gload16(BTh + gb, (void*)&sBh[f * 512]);
      gload16(BTl + gb, (void*)&sBl[f * 512]);
    }
    __syncthreads();

    const int wr = (w >> 1) * 4;
    const int wc = (w & 1) * 4;
    short8 ah[4], al[4], bh[4], bl[4];
#pragma unroll
    for (int i = 0; i < 4; ++i) {
      ah[i] = *(const short8*)&sAh[(wr + i) * 512 + l * 8];
      al[i] = *(const short8*)&sAl[(wr + i) * 512 + l * 8];
      bh[i] = *(const short8*)&sBh[(wc + i) * 512 + l * 8];
      bl[i] = *(const short8*)&sBl[(wc + i) * 512 + l * 8];
    }
#pragma unroll
    for (int mt = 0; mt < 4; ++mt)
#pragma unroll
      for (int nt = 0; nt < 4; ++nt) {
        acc[mt][nt] = __builtin_amdgcn_mfma_f32_16x16x32_bf16(ah[mt], bh[nt], acc[mt][nt], 0, 0, 0);
        acc[mt][nt] = __builtin_amdgcn_mfma_f32_16x16x32_bf16(ah[mt], bl[nt], acc[mt][nt], 0, 0, 0);
        acc[mt][nt] = __builtin_amdgcn_mfma_f32_16x16x32_bf16(al[mt], bh[nt], acc[mt][nt], 0, 0, 0);
      }
    __syncthreads();
  }

  const int rowb = row0 + (w >> 1) * 64;
  const int colb = col0 + (w & 1) * 64;
  const size_t obase = (mode == 0) ? (size_t)bz * M * N : (size_t)br * M * N;
#pragma unroll
  for (int mt = 0; mt < 4; ++mt)
#pragma unroll
    for (int nt = 0; nt < 4; ++nt) {
      const int col = colb + nt * 16 + lr;
#pragma unroll
      for (int j = 0; j < 4; ++j) {
        const int row = rowb + mt * 16 + lc * 4 + j;
        float v = acc[mt][nt][j];
        if (mode == 0) {
          Of[obase + (size_t)row * N + col] = v;
        } else if (mode == 1) {
          float mv = br ? mask1[row] : mask0[row];
          Of[obase + (size_t)row * N + col] = (v + bias[col]) * mv;
        } else {
          Ob[obase + (size_t)row * N + col] = f2bf(v * oscale);
        }
      }
    }
}

// ---------- LayerNorm: sum 4 conv partials + bsr, normalize, split to bf16 hi/lo ----------
__global__ __launch_bounds__(256) void ln_split(const float* __restrict__ xr,
                                                const float* __restrict__ bsr,
                                                const float* __restrict__ gamma,
                                                const float* __restrict__ beta,
                                                u16* __restrict__ xnh, u16* __restrict__ xnl) {
  const int row = blockIdx.x;
  const int br = blockIdx.y;
  const int t = threadIdx.x;
  const float* p = xr + (size_t)br * 4 * 524288 + (size_t)row * 512;
  const int c = t * 2;
  float v0 = p[c] + p[524288 + c] + p[1048576 + c] + p[1572864 + c] + bsr[c];
  float v1 = p[c + 1] + p[524288 + c + 1] + p[1048576 + c + 1] + p[1572864 + c + 1] + bsr[c + 1];
  float s = v0 + v1, sq = v0 * v0 + v1 * v1;
#pragma unroll
  for (int m = 1; m < 64; m <<= 1) {
    s += __shfl_xor(s, m, 64);
    sq += __shfl_xor(sq, m, 64);
  }
  __shared__ float ls[4], lsq[4];
  if ((t & 63) == 0) { ls[t >> 6] = s; lsq[t >> 6] = sq; }
  __syncthreads();
  s = ls[0] + ls[1] + ls[2] + ls[3];
  sq = lsq[0] + lsq[1] + lsq[2] + lsq[3];
  float mean = s * (1.0f / 512.0f);
  float var = sq * (1.0f / 512.0f) - mean * mean;
  float rs = rsqrtf(var + 1e-5f);
  size_t ob = (size_t)br * 524288 + (size_t)row * 512 + c;
  float y0 = (v0 - mean) * rs * gamma[c] + beta[c];
  float y1 = (v1 - mean) * rs * gamma[c + 1] + beta[c + 1];
  u16 h0 = f2bf(y0), h1 = f2bf(y1);
  xnh[ob] = h0; xnh[ob + 1] = h1;
  xnl[ob] = f2bf(y0 - bf2f(h0)); xnl[ob + 1] = f2bf(y1 - bf2f(h1));
}

// ---------- V transpose: kvb [br][m][1024] -> vt [br][h][d][m] ----------
__global__ __launch_bounds__(256) void vtb(const u16* __restrict__ kvb, u16* __restrict__ vt) {
  int idx = blockIdx.x * 256 + threadIdx.x;  // 2*8*64*1024
  int m = idx & 1023;
  int rest = idx >> 10;
  int d = rest & 63;
  int h = (rest >> 6) & 7;
  int br = rest >> 9;
  vt[idx] = kvb[(size_t)br * 1048576 + (size_t)m * 1024 + 512 + h * 64 + d];
}

// ---------- MFMA flash attention ----------
// qb [br][4096][512] bf16 (pre-scaled by 0.125), kvb [br][1024][1024], vt [br][8][64][1024]
// out: aoh/aol [br][4096][512] bf16 hi/lo (branch stride 4194304 elements)
__global__ __launch_bounds__(256) void attn_mfma(const u16* __restrict__ qb,
                                                 const u16* __restrict__ kvb,
                                                 const u16* __restrict__ vt,
                                                 u16* __restrict__ aoh, u16* __restrict__ aol) {
  const int t = threadIdx.x;
  const int w = t >> 6;
  const int l = t & 63;
  const int lr = l & 15;
  const int lc = l >> 4;
  const int hh = blockIdx.y;
  const int n0 = blockIdx.x * 64;
  const int br = blockIdx.z;
  qb += (size_t)br * 2097152;
  kvb += (size_t)br * 1048576;
  vt += (size_t)br * 524288;
  aoh += (size_t)br * 4194304;
  aol += (size_t)br * 4194304;

  __shared__ __align__(16) u16 Pl[4][1152];  // per-wave P: [16 q][72 kv]
  u16* Pw = &Pl[w][0];

  // Q^T B-fragments (held for whole loop)
  short8 bq[2];
  {
    const size_t qrow = (size_t)(n0 + w * 16 + lr) * 512 + hh * 64;
    bq[0] = *(const short8*)&qb[qrow + lc * 8];
    bq[1] = *(const short8*)&qb[qrow + 32 + lc * 8];
  }

  f32x4 acc[4];
#pragma unroll
  for (int i = 0; i < 4; ++i) acc[i] = (f32x4){0.f, 0.f, 0.f, 0.f};
  float mrun = -1e30f, lrun = 0.f;

  for (int m0 = 0; m0 < 1024; m0 += 64) {
    // S^T = K . Q^T : 4 frags of [16 kv][16 q]
    f32x4 st[4];
#pragma unroll
    for (int f = 0; f < 4; ++f) {
      const size_t krow = (size_t)(m0 + f * 16 + lr) * 1024 + hh * 64;
      short8 ka = *(const short8*)&kvb[krow + lc * 8];
      short8 kb = *(const short8*)&kvb[krow + 32 + lc * 8];
      f32x4 s = (f32x4){0.f, 0.f, 0.f, 0.f};
      s = __builtin_amdgcn_mfma_f32_16x16x32_bf16(ka, bq[0], s, 0, 0, 0);
      s = __builtin_amdgcn_mfma_f32_16x16x32_bf16(kb, bq[1], s, 0, 0, 0);
      st[f] = s;
    }
    // online softmax (lane holds 16 kv scores, all for q = lane&15)
    float tmax = -1e30f;
#pragma unroll
    for (int f = 0; f < 4; ++f)
#pragma unroll
      for (int j = 0; j < 4; ++j) tmax = fmaxf(tmax, st[f][j]);
    tmax = fmaxf(tmax, __shfl_xor(tmax, 16, 64));
    tmax = fmaxf(tmax, __shfl_xor(tmax, 32, 64));
    const float mnew = fmaxf(mrun, tmax);
    const float corr = __expf(mrun - mnew);
    float psum = 0.f;
#pragma unroll
    for (int f = 0; f < 4; ++f) {
      float p0 = __expf(st[f][0] - mnew);
      float p1 = __expf(st[f][1] - mnew);
      float p2 = __expf(st[f][2] - mnew);
      float p3 = __expf(st[f][3] - mnew);
      psum += p0 + p1 + p2 + p3;
      u64 pk = (u64)f2bf(p0) | ((u64)f2bf(p1) << 16) | ((u64)f2bf(p2) << 32) | ((u64)f2bf(p3) << 48);
      *(u64*)&Pw[lr * 72 + f * 16 + lc * 4] = pk;
    }
    psum += __shfl_xor(psum, 16, 64);
    psum += __shfl_xor(psum, 32, 64);
    lrun = lrun * corr + psum;
    mrun = mnew;
#pragma unroll
    for (int i = 0; i < 4; ++i) {
      acc[i][0] *= corr; acc[i][1] *= corr; acc[i][2] *= corr; acc[i][3] *= corr;
    }
    asm volatile("s_waitcnt lgkmcnt(0)" ::: "memory");
    // O^T += V^T . P^T
#pragma unroll
    for (int ks = 0; ks < 2; ++ks) {
      short8 bp = *(const short8*)&Pw[lr * 72 + ks * 32 + lc * 8];
#pragma unroll
      for (int db = 0; db < 4; ++db) {
        short8 av = *(const short8*)&vt[(size_t)(hh * 64 + db * 16 + lr) * 1024 + m0 + ks * 32 + lc * 8];
        acc[db] = __builtin_amdgcn_mfma_f32_16x16x32_bf16(av, bp, acc[db], 0, 0, 0);
      }
    }
  }

  // epilogue: normalize, transpose via LDS, split-write
  const float inv = 1.0f / lrun;
  __shared__ float Osh[64][68];
#pragma unroll
  for (int db = 0; db < 4; ++db)
#pragma unroll
    for (int j = 0; j < 4; ++j)
      Osh[w * 16 + lr][db * 16 + lc * 4 + j] = acc[db][j] * inv;
  __syncthreads();
  const int r = t >> 2;
  const int c0 = (t & 3) * 16;
  short8 hv0, hv1, lv0, lv1;
#pragma unroll
  for (int i = 0; i < 8; ++i) {
    float v = Osh[r][c0 + i];
    u16 hi = f2bf(v);
    hv0[i] = (short)hi;
    lv0[i] = (short)f2bf(v - bf2f(hi));
  }
#pragma unroll
  for (int i = 0; i < 8; ++i) {
    float v = Osh[r][c0 + 8 + i];
    u16 hi = f2bf(v);
    hv1[i] = (short)hi;
    lv1[i] = (short)f2bf(v - bf2f(hi));
  }
  const size_t ob = (size_t)(n0 + r) * 512 + hh * 64 + c0;
  *(short8*)&aoh[ob] = hv0;
  *(short8*)&aoh[ob + 8] = hv1;
  *(short8*)&aol[ob] = lv0;
  *(short8*)&aol[ob + 8] = lv1;
}

// ---------- token exchange ----------
__global__ __launch_bounds__(256) void exchange_f32(float* __restrict__ out,
                                                    const float* __restrict__ mask0,
                                                    const float* __restrict__ mask1) {
  int idx = blockIdx.x * 256 + threadIdx.x;
  int n = idx >> 9;
  float o0 = out[idx];
  float o1 = out[idx + NTOK * CDIM];
  bool k0 = mask0[n] >= 0.02f;
  bool k1 = mask1[n] >= 0.02f;
  out[idx] = k0 ? o0 : o1;
  out[idx + NTOK * CDIM] = k1 ? o1 : o0;
}

extern "C" void kernel_launch(void* const* d_in, const int* in_sizes, int n_in,
                              void* d_out, int out_size, void* d_ws, size_t ws_size,
                              hipStream_t stream) {
  const float* x0    = (const float*)d_in[0];
  const float* x1    = (const float*)d_in[1];
  const float* mask0 = (const float*)d_in[2];
  const float* mask1 = (const float*)d_in[3];
  const float* Wq    = (const float*)d_in[4];
  const float* Wkv   = (const float*)d_in[5];
  const float* Wsr   = (const float*)d_in[6];
  const float* bsr   = (const float*)d_in[7];
  const float* gamma = (const float*)d_in[8];
  const float* beta  = (const float*)d_in[9];
  const float* Wp    = (const float*)d_in[10];
  const float* bp    = (const float*)d_in[11];

  u16* U = (u16*)d_ws;
  size_t o = 0;
  u16* WqTh = U + o; o += 262144;  u16* WqTl = U + o; o += 262144;
  u16* WkvTh = U + o; o += 524288; u16* WkvTl = U + o; o += 524288;
  u16* WpTh = U + o; o += 262144;  u16* WpTl = U + o; o += 262144;
  u16* W2Th = U + o; o += 1048576; u16* W2Tl = U + o; o += 1048576;
  u16* x0h = U + o; o += 2097152;  u16* x0l = U + o; o += 2097152;
  u16* x1h = U + o; o += 2097152;  u16* x1l = U + o; o += 2097152;
  u16* qb2 = U + o; o += 4194304;          // 2 branches
  u16* xnh = U + o; o += 1048576;          // 2 branches
  u16* xnl = U + o; o += 1048576;
  u16* kvb = U + o; o += 2097152;          // 2 branches
  u16* vt  = U + o; o += 1048576;          // 2 branches
  float* xr = (float*)(U + o);             // 2 br x 4 parts x 524288 f32
  // ao aliases the x-split region (x dead after qproj+conv; attention runs later)
  u16* aoh = x0h;  // + br*4194304 -> x0h / x1h
  u16* aol = x0l;  // + br*4194304 -> x0l / x1l

  float* out = (float*)d_out;
  dim3 blk(256);

  // weight prep
  tsplit<<<1024, blk, 0, stream>>>(Wq, WqTh, WqTl, 512);
  tsplit<<<2048, blk, 0, stream>>>(Wkv, WkvTh, WkvTl, 1024);
  tsplit<<<1024, blk, 0, stream>>>(Wp, WpTh, WpTl, 512);
  wsr_split<<<4096, blk, 0, stream>>>(Wsr, W2Th, W2Tl);

  // x splits
  fsplit<<<8192, blk, 0, stream>>>(x0, x0h, x0l);
  fsplit<<<8192, blk, 0, stream>>>(x1, x1h, x1l);

  // q projection -> bf16 q (pre-scaled by hd^-0.5 = 0.125)
  gemm_sp<<<dim3(4, 32, 2), blk, 0, stream>>>(x0h, x0l, x1h, x1l, WqTh, WqTl,
      4096, 512, 512, 512, 1, 2, nullptr, qb2, nullptr, nullptr, nullptr, 0.125f, 0);

  // SR conv as gather-GEMM, split-K=4 -> f32 partials
  gemm_sp<<<dim3(4, 8, 8), blk, 0, stream>>>(x0h, x0l, x1h, x1l, W2Th, W2Tl,
      1024, 512, 2048, 512, 4, 0, xr, nullptr, nullptr, nullptr, nullptr, 1.0f, 1);

  // LayerNorm (+bsr) -> split bf16
  ln_split<<<dim3(1024, 2), blk, 0, stream>>>(xr, bsr, gamma, beta, xnh, xnl);

  // kv projection -> bf16 kv
  gemm_sp<<<dim3(8, 8, 2), blk, 0, stream>>>(xnh, xnl, xnh + 524288, xnl + 524288,
      WkvTh, WkvTl, 1024, 1024, 512, 512, 1, 2, nullptr, kvb, nullptr, nullptr, nullptr, 1.0f, 0);

  // V transpose
  vtb<<<4096, blk, 0, stream>>>(kvb, vt);

  // attention -> ao hi/lo
  attn_mfma<<<dim3(64, 8, 2), blk, 0, stream>>>(qb2, kvb, vt, aoh, aol);

  // output projection + bias + mask -> f32 out
  gemm_sp<<<dim3(4, 32, 2), blk, 0, stream>>>(x0h, x0l, x1h, x1l, WpTh, WpTl,
      4096, 512, 512, 512, 1, 1, out, nullptr, bp, mask0, mask1, 1.0f, 0);

  // token exchange
  exchange_f32<<<8192, blk, 0, stream>>>(out, mask0, mask1);
}